// Round 12
// baseline (1025.273 us; speedup 1.0000x reference)
//
#include <hip/hip_runtime.h>

#define USER_COUNT 200000
#define ITEM_COUNT 100000
#define N_NODES    300000   // USER_COUNT + ITEM_COUNT
#define EMB        64
#define BATCH      4096
#define NSLICE     4
#define SLICE_W    75000    // N_NODES / NSLICE

typedef unsigned int   u32;
typedef unsigned long long u64;
typedef unsigned char  u8;
typedef float float2v  __attribute__((ext_vector_type(2)));
typedef float float8v  __attribute__((ext_vector_type(8)));
typedef u32   u32x2    __attribute__((ext_vector_type(2)));

// ---------------------------------------------------------------------------
// fp8 (OCP e4m3 on gfx950) pack/unpack via HW converters.
// ---------------------------------------------------------------------------
static __device__ __forceinline__ u32 pk4_fp8(float a, float b, float c, float d) {
    u32 w = 0;
    w = (u32)__builtin_amdgcn_cvt_pk_fp8_f32(a, b, (int)w, false);
    w = (u32)__builtin_amdgcn_cvt_pk_fp8_f32(c, d, (int)w, true);
    return w;
}
static __device__ __forceinline__ void unpk4_fp8(u32 w, float* o) {
    float2v lo = __builtin_amdgcn_cvt_pk_f32_fp8((int)w, false);
    float2v hi = __builtin_amdgcn_cvt_pk_f32_fp8((int)w, true);
    o[0] = lo.x; o[1] = lo.y; o[2] = hi.x; o[3] = hi.y;
}

static __device__ __forceinline__ int slice_of(int c) {
    return (c >= 2 * SLICE_W) ? ((c >= 3 * SLICE_W) ? 3 : 2)
                              : ((c >= SLICE_W) ? 1 : 0);
}

// ---------------------------------------------------------------------------
// Fused prep: (a) row_ptr from sorted COO rows; (b) ego -> fp8 convert.
// ---------------------------------------------------------------------------
__global__ void prep_kernel(const int* __restrict__ row,
                            int* __restrict__ ptr,
                            const float* __restrict__ ue,
                            const float* __restrict__ ie,
                            u32* __restrict__ out8, int nnz) {
    size_t t = (size_t)blockIdx.x * blockDim.x + threadIdx.x;

    if (t < (size_t)nnz) {
        int i = (int)t;
        int r  = row[i];
        int rp = (i == 0) ? -1 : row[i - 1];
        for (int rr = rp + 1; rr <= r; ++rr) ptr[rr] = i;
        if (i == nnz - 1) {
            for (int rr = r + 1; rr <= N_NODES; ++rr) ptr[rr] = nnz;
        }
    }

    const size_t total = (size_t)N_NODES * EMB / 4;
    if (t < total) {
        size_t base = t * 4;
        const size_t ub = (size_t)USER_COUNT * EMB;
        const float* src = (base < ub) ? (ue + base) : (ie + (base - ub));
        float4 v = *(const float4*)src;
        out8[t] = pk4_fp8(v.x, v.y, v.z, v.w);
    }
}

// ---------------------------------------------------------------------------
// Bucket each row's edges by col-slice (stable within-row partition).
// One wave per row. Writes offA[s][r] (start of slice-s sub-segment, absolute
// edge index; end = offA[s+1][r] or ptr[r+1]) and the reordered colB/valB.
// ---------------------------------------------------------------------------
__global__ __launch_bounds__(256) void bucket_kernel(
        const int* __restrict__ col, const float* __restrict__ val,
        const int* __restrict__ ptr, int* __restrict__ offA,
        int* __restrict__ colB, float* __restrict__ valB) {
    int rowi = (int)((blockIdx.x * blockDim.x + threadIdx.x) >> 6);
    if (rowi >= N_NODES) return;
    int lane = (int)(threadIdx.x & 63);
    int p0 = ptr[rowi], p1 = ptr[rowi + 1];

    // pass A: per-slice totals
    int c0 = 0, c1 = 0, c2 = 0, c3 = 0;
    for (int j0 = p0; j0 < p1; j0 += 64) {
        int j = j0 + lane;
        bool act = j < p1;
        int c = col[act ? j : (p1 - 1)];
        int s = slice_of(c);
        c0 += (int)__popcll(__ballot(act && s == 0));
        c1 += (int)__popcll(__ballot(act && s == 1));
        c2 += (int)__popcll(__ballot(act && s == 2));
        c3 += (int)__popcll(__ballot(act && s == 3));
    }
    int off0 = p0, off1 = off0 + c0, off2 = off1 + c1, off3 = off2 + c2;
    if (lane == 0) {
        offA[0 * N_NODES + rowi] = off0;
        offA[1 * N_NODES + rowi] = off1;
        offA[2 * N_NODES + rowi] = off2;
        offA[3 * N_NODES + rowi] = off3;
    }

    // pass B: stable scatter
    int w0 = 0, w1 = 0, w2 = 0, w3 = 0;
    u64 below = ((u64)1 << lane) - 1;
    for (int j0 = p0; j0 < p1; j0 += 64) {
        int j = j0 + lane;
        bool act = j < p1;
        int jc = act ? j : (p1 - 1);
        int c = col[jc];
        float v = val[jc];
        int s = slice_of(c);
        u64 b0 = __ballot(act && s == 0);
        u64 b1 = __ballot(act && s == 1);
        u64 b2 = __ballot(act && s == 2);
        u64 b3 = __ballot(act && s == 3);
        u64 bs = (s == 0) ? b0 : (s == 1) ? b1 : (s == 2) ? b2 : b3;
        int wb = (s == 0) ? w0 : (s == 1) ? w1 : (s == 2) ? w2 : w3;
        int ob = (s == 0) ? off0 : (s == 1) ? off1 : (s == 2) ? off2 : off3;
        int dest = ob + wb + (int)__popcll(bs & below);
        if (act) { colB[dest] = c; valB[dest] = v; }
        w0 += (int)__popcll(b0);
        w1 += (int)__popcll(b1);
        w2 += (int)__popcll(b2);
        w3 += (int)__popcll(b3);
    }
}

// ---------------------------------------------------------------------------
// Mark nodes whose h2 row is actually consumed.
// ---------------------------------------------------------------------------
__global__ void mark_needed(const int* __restrict__ users,
                            const int* __restrict__ items,
                            const int* __restrict__ col,
                            const int* __restrict__ ptr,
                            u32* __restrict__ flag) {
    int slot = (int)((blockIdx.x * blockDim.x + threadIdx.x) >> 6);
    if (slot >= 2 * BATCH) return;
    int lane = threadIdx.x & 63;
    int row = (slot < BATCH) ? users[slot] : (items[slot - BATCH] + USER_COUNT);
    if (lane == 0) flag[row] = 1;
    int p0 = ptr[row];
    int p1 = ptr[row + 1];
    for (int j = p0 + lane; j < p1; j += 64) flag[col[j]] = 1;
}

#define SLOT_REDUCE(ACC)                                              \
    _Pragma("unroll")                                                 \
    for (int q = 0; q < 8; ++q) {                                     \
        ACC[q] += __shfl_xor(ACC[q], 8, 64);                          \
        ACC[q] += __shfl_xor(ACC[q], 16, 64);                         \
        ACC[q] += __shfl_xor(ACC[q], 32, 64);                         \
    }

// ---------------------------------------------------------------------------
// Core accumulation over one segment [p0,p1). 8 slots x 8 lanes; TILE=32
// staged; final tile predicated (clamped index, masked weight).
// ---------------------------------------------------------------------------
static __device__ __forceinline__ float8v row_accum(
        const u8* __restrict__ x, const int* __restrict__ col,
        const float* __restrict__ val, int p0, int p1, int e, int d) {
    float8v a0 = {0,0,0,0,0,0,0,0};
    float8v a1 = {0,0,0,0,0,0,0,0};
    float8v a2 = {0,0,0,0,0,0,0,0};
    float8v a3 = {0,0,0,0,0,0,0,0};

    int base = p0;
    for (; base + 32 <= p1; base += 32) {
        int j0 = base + e, j1 = j0 + 8, j2 = j0 + 16, j3 = j0 + 24;
        int   c0 = __builtin_nontemporal_load(col + j0);
        int   c1 = __builtin_nontemporal_load(col + j1);
        int   c2 = __builtin_nontemporal_load(col + j2);
        int   c3 = __builtin_nontemporal_load(col + j3);
        float v0 = __builtin_nontemporal_load(val + j0);
        float v1 = __builtin_nontemporal_load(val + j1);
        float v2 = __builtin_nontemporal_load(val + j2);
        float v3 = __builtin_nontemporal_load(val + j3);
        u32x2 h0 = *(const u32x2*)(x + (size_t)c0 * EMB + d);
        u32x2 h1 = *(const u32x2*)(x + (size_t)c1 * EMB + d);
        u32x2 h2 = *(const u32x2*)(x + (size_t)c2 * EMB + d);
        u32x2 h3 = *(const u32x2*)(x + (size_t)c3 * EMB + d);
        float xf[8];
        unpk4_fp8(h0.x, xf); unpk4_fp8(h0.y, xf + 4);
        #pragma unroll
        for (int q = 0; q < 8; ++q) a0[q] += v0 * xf[q];
        unpk4_fp8(h1.x, xf); unpk4_fp8(h1.y, xf + 4);
        #pragma unroll
        for (int q = 0; q < 8; ++q) a1[q] += v1 * xf[q];
        unpk4_fp8(h2.x, xf); unpk4_fp8(h2.y, xf + 4);
        #pragma unroll
        for (int q = 0; q < 8; ++q) a2[q] += v2 * xf[q];
        unpk4_fp8(h3.x, xf); unpk4_fp8(h3.y, xf + 4);
        #pragma unroll
        for (int q = 0; q < 8; ++q) a3[q] += v3 * xf[q];
    }

    if (base < p1) {
        int p1m1 = p1 - 1;
        int jj0 = base + e, jj1 = jj0 + 8, jj2 = jj0 + 16, jj3 = jj0 + 24;
        int jc0 = (jj0 < p1) ? jj0 : p1m1;
        int jc1 = (jj1 < p1) ? jj1 : p1m1;
        int jc2 = (jj2 < p1) ? jj2 : p1m1;
        int jc3 = (jj3 < p1) ? jj3 : p1m1;
        int   c0 = __builtin_nontemporal_load(col + jc0);
        int   c1 = __builtin_nontemporal_load(col + jc1);
        int   c2 = __builtin_nontemporal_load(col + jc2);
        int   c3 = __builtin_nontemporal_load(col + jc3);
        float v0 = __builtin_nontemporal_load(val + jc0);
        float v1 = __builtin_nontemporal_load(val + jc1);
        float v2 = __builtin_nontemporal_load(val + jc2);
        float v3 = __builtin_nontemporal_load(val + jc3);
        v0 = (jj0 < p1) ? v0 : 0.0f;
        v1 = (jj1 < p1) ? v1 : 0.0f;
        v2 = (jj2 < p1) ? v2 : 0.0f;
        v3 = (jj3 < p1) ? v3 : 0.0f;
        u32x2 h0 = *(const u32x2*)(x + (size_t)c0 * EMB + d);
        u32x2 h1 = *(const u32x2*)(x + (size_t)c1 * EMB + d);
        u32x2 h2 = *(const u32x2*)(x + (size_t)c2 * EMB + d);
        u32x2 h3 = *(const u32x2*)(x + (size_t)c3 * EMB + d);
        float xf[8];
        unpk4_fp8(h0.x, xf); unpk4_fp8(h0.y, xf + 4);
        #pragma unroll
        for (int q = 0; q < 8; ++q) a0[q] += v0 * xf[q];
        unpk4_fp8(h1.x, xf); unpk4_fp8(h1.y, xf + 4);
        #pragma unroll
        for (int q = 0; q < 8; ++q) a1[q] += v1 * xf[q];
        unpk4_fp8(h2.x, xf); unpk4_fp8(h2.y, xf + 4);
        #pragma unroll
        for (int q = 0; q < 8; ++q) a2[q] += v2 * xf[q];
        unpk4_fp8(h3.x, xf); unpk4_fp8(h3.y, xf + 4);
        #pragma unroll
        for (int q = 0; q < 8; ++q) a3[q] += v3 * xf[q];
    }

    #pragma unroll
    for (int q = 0; q < 8; ++q) a0[q] += (a1[q] + a2[q]) + a3[q];
    return a0;
}

// ---------------------------------------------------------------------------
// Slice SpMM: block b -> slice s = b&3, rows 4*(b>>2)..+3 (one wave each).
// With round-robin block->XCD dispatch, XCD k sees only slice k%4 -> its
// gathers stay within a 4.8 MB sub-table (L2-resident).
// Writes fp8 partials partial[s][row][64].
// ---------------------------------------------------------------------------
template <bool USE_FLAG>
__global__ __launch_bounds__(256) void spmm_slice(
        const u8* __restrict__ x, const int* __restrict__ colB,
        const float* __restrict__ valB, const int* __restrict__ offA,
        const int* __restrict__ ptr, const u32* __restrict__ flag,
        u8* __restrict__ partial) {
    int b = blockIdx.x;
    int s = b & 3;
    int row = ((b >> 2) << 2) + (int)(threadIdx.x >> 6);
    if (row >= N_NODES) return;
    if (USE_FLAG && flag[row] == 0) return;
    int lane = threadIdx.x & 63;
    int e = lane >> 3;
    int d = (lane & 7) << 3;

    int p0 = offA[s * N_NODES + row];
    int p1 = (s < 3) ? offA[(s + 1) * N_NODES + row] : ptr[row + 1];

    float8v a = row_accum(x, colB, valB, p0, p1, e, d);
    SLOT_REDUCE(a);

    if (e == 0) {
        u32x2 o;
        o.x = pk4_fp8(a[0], a[1], a[2], a[3]);
        o.y = pk4_fp8(a[4], a[5], a[6], a[7]);
        __builtin_nontemporal_store(
            o, (u32x2*)(partial + ((size_t)s * N_NODES + row) * EMB + d));
    }
}

// ---------------------------------------------------------------------------
// Reduce: h[r] = fp8( sum_s partial[s][r] ).  Streaming, 8 B per thread.
// ---------------------------------------------------------------------------
__global__ void reduce_partials(const u8* __restrict__ partial,
                                u8* __restrict__ y) {
    size_t t = (size_t)blockIdx.x * blockDim.x + threadIdx.x;
    const size_t total = (size_t)N_NODES * (EMB / 8);
    if (t >= total) return;
    size_t byteoff = t * 8;
    float acc[8] = {0,0,0,0,0,0,0,0};
    #pragma unroll
    for (int s = 0; s < NSLICE; ++s) {
        u32x2 wv = *(const u32x2*)(partial + (size_t)s * N_NODES * EMB + byteoff);
        float f[8];
        unpk4_fp8(wv.x, f); unpk4_fp8(wv.y, f + 4);
        #pragma unroll
        for (int q = 0; q < 8; ++q) acc[q] += f[q];
    }
    u32x2 o;
    o.x = pk4_fp8(acc[0], acc[1], acc[2], acc[3]);
    o.y = pk4_fp8(acc[4], acc[5], acc[6], acc[7]);
    __builtin_nontemporal_store(o, (u32x2*)(y + byteoff));
}

// ---------------------------------------------------------------------------
// Fallback full SpMM (R11 path): one wave per row over original col/val.
// ---------------------------------------------------------------------------
template <bool USE_FLAG>
__global__ __launch_bounds__(256) void spmm_fp8(
        const u8* __restrict__ x, const int* __restrict__ col,
        const float* __restrict__ val, const int* __restrict__ ptr,
        const u32* __restrict__ flag, u8* __restrict__ y) {
    int wave = (int)((blockIdx.x * blockDim.x + threadIdx.x) >> 6);
    int lane = threadIdx.x & 63;
    if (wave >= N_NODES) return;
    if (USE_FLAG && flag[wave] == 0) return;
    int e = lane >> 3;
    int d = (lane & 7) << 3;
    int p0 = ptr[wave];
    int p1 = ptr[wave + 1];
    float8v a = row_accum(x, col, val, p0, p1, e, d);
    SLOT_REDUCE(a);
    if (e == 0) {
        u32x2 o;
        o.x = pk4_fp8(a[0], a[1], a[2], a[3]);
        o.y = pk4_fp8(a[4], a[5], a[6], a[7]);
        __builtin_nontemporal_store(o, (u32x2*)(y + (size_t)wave * EMB + d));
    }
}

// ---------------------------------------------------------------------------
// Finalize: out[slot] = 0.25*(ego_f32[row] + h1[row] + h2[row] + (A*h2)[row]).
// ---------------------------------------------------------------------------
__global__ __launch_bounds__(256) void finalize(
        const u8* __restrict__ h1, const u8* __restrict__ h2,
        const float* __restrict__ ue, const float* __restrict__ ie,
        const int* __restrict__ col, const float* __restrict__ val,
        const int* __restrict__ ptr, const int* __restrict__ users,
        const int* __restrict__ items, float* __restrict__ out) {
    int slot = (int)((blockIdx.x * blockDim.x + threadIdx.x) >> 6);
    if (slot >= 2 * BATCH) return;
    int lane = threadIdx.x & 63;
    int e = lane >> 3;
    int d = (lane & 7) << 3;

    int row = (slot < BATCH) ? users[slot] : (items[slot - BATCH] + USER_COUNT);
    int p0 = ptr[row];
    int p1 = ptr[row + 1];

    float8v a = row_accum(h2, col, val, p0, p1, e, d);
    SLOT_REDUCE(a);

    if (e == 0) {
        const float* eg = ((row < USER_COUNT) ? (ue + (size_t)row * EMB)
                                              : (ie + (size_t)(row - USER_COUNT) * EMB)) + d;
        u32x2 w1 = *(const u32x2*)(h1 + (size_t)row * EMB + d);
        u32x2 w2 = *(const u32x2*)(h2 + (size_t)row * EMB + d);
        float f1[8], f2[8];
        unpk4_fp8(w1.x, f1); unpk4_fp8(w1.y, f1 + 4);
        unpk4_fp8(w2.x, f2); unpk4_fp8(w2.y, f2 + 4);
        float4 o0, o1;
        o0.x = 0.25f * (eg[0] + f1[0] + f2[0] + a[0]);
        o0.y = 0.25f * (eg[1] + f1[1] + f2[1] + a[1]);
        o0.z = 0.25f * (eg[2] + f1[2] + f2[2] + a[2]);
        o0.w = 0.25f * (eg[3] + f1[3] + f2[3] + a[3]);
        o1.x = 0.25f * (eg[4] + f1[4] + f2[4] + a[4]);
        o1.y = 0.25f * (eg[5] + f1[5] + f2[5] + a[5]);
        o1.z = 0.25f * (eg[6] + f1[6] + f2[6] + a[6]);
        o1.w = 0.25f * (eg[7] + f1[7] + f2[7] + a[7]);
        float* o = out + (size_t)slot * EMB + d;
        *(float4*)o       = o0;
        *(float4*)(o + 4) = o1;
    }
}

extern "C" void kernel_launch(void* const* d_in, const int* in_sizes, int n_in,
                              void* d_out, int out_size, void* d_ws, size_t ws_size,
                              hipStream_t stream) {
    const float* user_emb = (const float*)d_in[0];
    const float* item_emb = (const float*)d_in[1];
    const int*   adj_row  = (const int*)d_in[2];
    const int*   adj_col  = (const int*)d_in[3];
    const float* adj_val  = (const float*)d_in[4];
    const int*   users    = (const int*)d_in[5];
    const int*   items    = (const int*)d_in[6];
    float*       out      = (float*)d_out;
    const int    nnz      = in_sizes[2];

    char* ws = (char*)d_ws;
    const size_t hbytes  = (size_t)N_NODES * EMB;            // 19.2 MB fp8 table
    const size_t ibytes  = (size_t)(N_NODES + 64) * sizeof(int);
    u8*  ego8 = (u8*)(ws);
    u8*  h1   = (u8*)(ws + hbytes);
    u8*  h2   = (u8*)(ws + 2 * hbytes);
    int* ptr  = (int*)(ws + 3 * hbytes);
    u32* flag = (u32*)(ws + 3 * hbytes + ibytes);
    int*   offA    = (int*)(ws + 3 * hbytes + 2 * ibytes);
    int*   colB    = (int*)((char*)offA + (size_t)NSLICE * N_NODES * sizeof(int));
    float* valB    = (float*)((char*)colB + (size_t)nnz * sizeof(int));
    u8*    partial = (u8*)((char*)valB + (size_t)nnz * sizeof(float));
    size_t need = ((char*)partial + (size_t)NSLICE * hbytes) - ws;
    bool sliced = need <= ws_size;

    (void)hipMemsetAsync(flag, 0, (size_t)N_NODES * sizeof(u32), stream);

    // 1) fused prep: row_ptr + ego->fp8
    prep_kernel<<<(nnz + 255) / 256, 256, 0, stream>>>(
        adj_row, ptr, user_emb, item_emb, (u32*)ego8, nnz);

    // 2) mark rows whose h2 is consumed
    mark_needed<<<(2 * BATCH + 3) / 4, 256, 0, stream>>>(
        users, items, adj_col, ptr, flag);

    const int spmm_blocks = (N_NODES + 3) / 4;
    const int sel_blocks  = (2 * BATCH + 3) / 4;

    if (sliced) {
        // 3) bucket edges by col-slice (within-row stable partition)
        bucket_kernel<<<spmm_blocks, 256, 0, stream>>>(
            adj_col, adj_val, ptr, offA, colB, valB);

        const int slice_blocks = NSLICE * ((N_NODES + 3) / 4);
        const int red_blocks   = (int)(((size_t)N_NODES * (EMB / 8) + 255) / 256);

        // 4) h1 = A * ego8 via slice partials
        spmm_slice<false><<<slice_blocks, 256, 0, stream>>>(
            ego8, colB, valB, offA, ptr, nullptr, partial);
        reduce_partials<<<red_blocks, 256, 0, stream>>>(partial, h1);

        // 5) h2 = A * h1 (flagged rows only)
        spmm_slice<true><<<slice_blocks, 256, 0, stream>>>(
            h1, colB, valB, offA, ptr, flag, partial);
        reduce_partials<<<red_blocks, 256, 0, stream>>>(partial, h2);
    } else {
        // Fallback: R11 monolithic pull SpMMs
        spmm_fp8<false><<<spmm_blocks, 256, 0, stream>>>(
            ego8, adj_col, adj_val, ptr, nullptr, h1);
        spmm_fp8<true><<<spmm_blocks, 256, 0, stream>>>(
            h1, adj_col, adj_val, ptr, flag, h2);
    }

    // 6) out = 0.25*(ego[sel] + h1[sel] + h2[sel] + (A*h2)[sel])
    finalize<<<sel_blocks, 256, 0, stream>>>(
        h1, h2, user_emb, item_emb, adj_col, adj_val, ptr, users, items, out);
}

// Round 13
// 340.743 us; speedup vs baseline: 3.0089x; 3.0089x over previous
//
#include <hip/hip_runtime.h>

#define USER_COUNT 200000
#define ITEM_COUNT 100000
#define N_NODES    300000   // USER_COUNT + ITEM_COUNT
#define EMB        64
#define BATCH      4096

typedef unsigned int   u32;
typedef unsigned char  u8;
typedef float float2v  __attribute__((ext_vector_type(2)));
typedef float float8v  __attribute__((ext_vector_type(8)));
typedef u32   u32x2    __attribute__((ext_vector_type(2)));

// ---------------------------------------------------------------------------
// fp8 (OCP e4m3 on gfx950) pack/unpack via HW converters.
// ---------------------------------------------------------------------------
static __device__ __forceinline__ u32 pk4_fp8(float a, float b, float c, float d) {
    u32 w = 0;
    w = (u32)__builtin_amdgcn_cvt_pk_fp8_f32(a, b, (int)w, false); // low half
    w = (u32)__builtin_amdgcn_cvt_pk_fp8_f32(c, d, (int)w, true);  // high half
    return w;
}
static __device__ __forceinline__ void unpk4_fp8(u32 w, float* o) {
    float2v lo = __builtin_amdgcn_cvt_pk_f32_fp8((int)w, false);
    float2v hi = __builtin_amdgcn_cvt_pk_f32_fp8((int)w, true);
    o[0] = lo.x; o[1] = lo.y; o[2] = hi.x; o[3] = hi.y;
}

// ---------------------------------------------------------------------------
// Fused prep: (a) row_ptr from sorted COO rows; (b) ego -> fp8 convert.
// Independent ranges, one launch. t < nnz : rowptr ; t < N_NODES*EMB/4 : cvt.
// ---------------------------------------------------------------------------
__global__ void prep_kernel(const int* __restrict__ row,
                            int* __restrict__ ptr,
                            const float* __restrict__ ue,
                            const float* __restrict__ ie,
                            u32* __restrict__ out8, int nnz) {
    size_t t = (size_t)blockIdx.x * blockDim.x + threadIdx.x;

    if (t < (size_t)nnz) {
        int i = (int)t;
        int r  = row[i];
        int rp = (i == 0) ? -1 : row[i - 1];
        for (int rr = rp + 1; rr <= r; ++rr) ptr[rr] = i;
        if (i == nnz - 1) {
            for (int rr = r + 1; rr <= N_NODES; ++rr) ptr[rr] = nnz;
        }
    }

    const size_t total = (size_t)N_NODES * EMB / 4;
    if (t < total) {
        size_t base = t * 4;
        const size_t ub = (size_t)USER_COUNT * EMB;
        const float* src = (base < ub) ? (ue + base) : (ie + (base - ub));
        float4 v = *(const float4*)src;
        out8[t] = pk4_fp8(v.x, v.y, v.z, v.w);
    }
}

// ---------------------------------------------------------------------------
// Mark nodes whose h2 row is actually consumed (sel rows + their neighbors).
// ---------------------------------------------------------------------------
__global__ void mark_needed(const int* __restrict__ users,
                            const int* __restrict__ items,
                            const int* __restrict__ col,
                            const int* __restrict__ ptr,
                            u32* __restrict__ flag) {
    int slot = (int)((blockIdx.x * blockDim.x + threadIdx.x) >> 6);
    if (slot >= 2 * BATCH) return;
    int lane = threadIdx.x & 63;
    int row = (slot < BATCH) ? users[slot] : (items[slot - BATCH] + USER_COUNT);
    if (lane == 0) flag[row] = 1;
    int p0 = ptr[row];
    int p1 = ptr[row + 1];
    for (int j = p0 + lane; j < p1; j += 64) flag[col[j]] = 1;
}

#define SLOT_REDUCE(ACC)                                              \
    _Pragma("unroll")                                                 \
    for (int q = 0; q < 8; ++q) {                                     \
        ACC[q] += __shfl_xor(ACC[q], 8, 64);                          \
        ACC[q] += __shfl_xor(ACC[q], 16, 64);                         \
        ACC[q] += __shfl_xor(ACC[q], 32, 64);                         \
    }

// ---------------------------------------------------------------------------
// Core accumulation over one row segment [p0,p1).
//   e = lane>>3 : edge slot (8 concurrent edges); d = (lane&7)*8 byte offset.
// TILE=32: stage 4 col/val pairs, issue 4 row-gathers back-to-back
// (32 independent 64B lines in flight per wave), then unpack+FMA.
// Wave-uniform trip count; final tile fully predicated -> zero divergence.
// ---------------------------------------------------------------------------
static __device__ __forceinline__ float8v row_accum(
        const u8* __restrict__ x, const int* __restrict__ col,
        const float* __restrict__ val, int p0, int p1, int e, int d) {
    float8v a0 = {0,0,0,0,0,0,0,0};
    float8v a1 = {0,0,0,0,0,0,0,0};
    float8v a2 = {0,0,0,0,0,0,0,0};
    float8v a3 = {0,0,0,0,0,0,0,0};

    int base = p0;
    for (; base + 32 <= p1; base += 32) {            // clean full tiles
        int j0 = base + e, j1 = j0 + 8, j2 = j0 + 16, j3 = j0 + 24;
        int   c0 = __builtin_nontemporal_load(col + j0);
        int   c1 = __builtin_nontemporal_load(col + j1);
        int   c2 = __builtin_nontemporal_load(col + j2);
        int   c3 = __builtin_nontemporal_load(col + j3);
        float v0 = __builtin_nontemporal_load(val + j0);
        float v1 = __builtin_nontemporal_load(val + j1);
        float v2 = __builtin_nontemporal_load(val + j2);
        float v3 = __builtin_nontemporal_load(val + j3);
        u32x2 h0 = *(const u32x2*)(x + (size_t)c0 * EMB + d);
        u32x2 h1 = *(const u32x2*)(x + (size_t)c1 * EMB + d);
        u32x2 h2 = *(const u32x2*)(x + (size_t)c2 * EMB + d);
        u32x2 h3 = *(const u32x2*)(x + (size_t)c3 * EMB + d);
        float xf[8];
        unpk4_fp8(h0.x, xf); unpk4_fp8(h0.y, xf + 4);
        #pragma unroll
        for (int q = 0; q < 8; ++q) a0[q] += v0 * xf[q];
        unpk4_fp8(h1.x, xf); unpk4_fp8(h1.y, xf + 4);
        #pragma unroll
        for (int q = 0; q < 8; ++q) a1[q] += v1 * xf[q];
        unpk4_fp8(h2.x, xf); unpk4_fp8(h2.y, xf + 4);
        #pragma unroll
        for (int q = 0; q < 8; ++q) a2[q] += v2 * xf[q];
        unpk4_fp8(h3.x, xf); unpk4_fp8(h3.y, xf + 4);
        #pragma unroll
        for (int q = 0; q < 8; ++q) a3[q] += v3 * xf[q];
    }

    if (base < p1) {                                 // one predicated tile
        int p1m1 = p1 - 1;
        int jj0 = base + e, jj1 = jj0 + 8, jj2 = jj0 + 16, jj3 = jj0 + 24;
        int jc0 = (jj0 < p1) ? jj0 : p1m1;
        int jc1 = (jj1 < p1) ? jj1 : p1m1;
        int jc2 = (jj2 < p1) ? jj2 : p1m1;
        int jc3 = (jj3 < p1) ? jj3 : p1m1;
        int   c0 = __builtin_nontemporal_load(col + jc0);
        int   c1 = __builtin_nontemporal_load(col + jc1);
        int   c2 = __builtin_nontemporal_load(col + jc2);
        int   c3 = __builtin_nontemporal_load(col + jc3);
        float v0 = __builtin_nontemporal_load(val + jc0);
        float v1 = __builtin_nontemporal_load(val + jc1);
        float v2 = __builtin_nontemporal_load(val + jc2);
        float v3 = __builtin_nontemporal_load(val + jc3);
        v0 = (jj0 < p1) ? v0 : 0.0f;
        v1 = (jj1 < p1) ? v1 : 0.0f;
        v2 = (jj2 < p1) ? v2 : 0.0f;
        v3 = (jj3 < p1) ? v3 : 0.0f;
        u32x2 h0 = *(const u32x2*)(x + (size_t)c0 * EMB + d);
        u32x2 h1 = *(const u32x2*)(x + (size_t)c1 * EMB + d);
        u32x2 h2 = *(const u32x2*)(x + (size_t)c2 * EMB + d);
        u32x2 h3 = *(const u32x2*)(x + (size_t)c3 * EMB + d);
        float xf[8];
        unpk4_fp8(h0.x, xf); unpk4_fp8(h0.y, xf + 4);
        #pragma unroll
        for (int q = 0; q < 8; ++q) a0[q] += v0 * xf[q];
        unpk4_fp8(h1.x, xf); unpk4_fp8(h1.y, xf + 4);
        #pragma unroll
        for (int q = 0; q < 8; ++q) a1[q] += v1 * xf[q];
        unpk4_fp8(h2.x, xf); unpk4_fp8(h2.y, xf + 4);
        #pragma unroll
        for (int q = 0; q < 8; ++q) a2[q] += v2 * xf[q];
        unpk4_fp8(h3.x, xf); unpk4_fp8(h3.y, xf + 4);
        #pragma unroll
        for (int q = 0; q < 8; ++q) a3[q] += v3 * xf[q];
    }

    #pragma unroll
    for (int q = 0; q < 8; ++q) a0[q] += (a1[q] + a2[q]) + a3[q];
    return a0;
}

// ---------------------------------------------------------------------------
// Full SpMM (fp8 in / fp8 out): one wave per row.
// USE_FLAG: skip rows whose output is never consumed.
// ---------------------------------------------------------------------------
template <bool USE_FLAG>
__global__ __launch_bounds__(256) void spmm_fp8(
        const u8* __restrict__ x, const int* __restrict__ col,
        const float* __restrict__ val, const int* __restrict__ ptr,
        const u32* __restrict__ flag, u8* __restrict__ y) {
    int wave = (int)((blockIdx.x * blockDim.x + threadIdx.x) >> 6);
    int lane = threadIdx.x & 63;
    if (wave >= N_NODES) return;
    if (USE_FLAG && flag[wave] == 0) return;
    int e = lane >> 3;          // 0..7
    int d = (lane & 7) << 3;    // byte offset 0,8,...,56

    int p0 = ptr[wave];
    int p1 = ptr[wave + 1];

    float8v a = row_accum(x, col, val, p0, p1, e, d);
    SLOT_REDUCE(a);

    if (e == 0) {
        u32x2 o;
        o.x = pk4_fp8(a[0], a[1], a[2], a[3]);
        o.y = pk4_fp8(a[4], a[5], a[6], a[7]);
        __builtin_nontemporal_store(o, (u32x2*)(y + (size_t)wave * EMB + d));
    }
}

// ---------------------------------------------------------------------------
// Finalize: one wave per output slot.
//   out[slot] = 0.25 * ( ego_f32[row] + h1[row] + h2[row] + (A*h2)[row] )
// Layer-3 sel-SpMM fused with all three gathers and the scale; single pass
// over out, no read-modify-write round trips.
// ---------------------------------------------------------------------------
__global__ __launch_bounds__(256) void finalize(
        const u8* __restrict__ h1, const u8* __restrict__ h2,
        const float* __restrict__ ue, const float* __restrict__ ie,
        const int* __restrict__ col, const float* __restrict__ val,
        const int* __restrict__ ptr, const int* __restrict__ users,
        const int* __restrict__ items, float* __restrict__ out) {
    int slot = (int)((blockIdx.x * blockDim.x + threadIdx.x) >> 6);
    if (slot >= 2 * BATCH) return;
    int lane = threadIdx.x & 63;
    int e = lane >> 3;
    int d = (lane & 7) << 3;

    int row = (slot < BATCH) ? users[slot] : (items[slot - BATCH] + USER_COUNT);
    int p0 = ptr[row];
    int p1 = ptr[row + 1];

    float8v a = row_accum(h2, col, val, p0, p1, e, d);
    SLOT_REDUCE(a);

    if (e == 0) {
        // d = byte offset into fp8 row = element offset into f32 row (8 dims)
        const float* eg = ((row < USER_COUNT) ? (ue + (size_t)row * EMB)
                                              : (ie + (size_t)(row - USER_COUNT) * EMB)) + d;
        u32x2 w1 = *(const u32x2*)(h1 + (size_t)row * EMB + d);
        u32x2 w2 = *(const u32x2*)(h2 + (size_t)row * EMB + d);
        float f1[8], f2[8];
        unpk4_fp8(w1.x, f1); unpk4_fp8(w1.y, f1 + 4);
        unpk4_fp8(w2.x, f2); unpk4_fp8(w2.y, f2 + 4);
        float4 o0, o1;
        o0.x = 0.25f * (eg[0] + f1[0] + f2[0] + a[0]);
        o0.y = 0.25f * (eg[1] + f1[1] + f2[1] + a[1]);
        o0.z = 0.25f * (eg[2] + f1[2] + f2[2] + a[2]);
        o0.w = 0.25f * (eg[3] + f1[3] + f2[3] + a[3]);
        o1.x = 0.25f * (eg[4] + f1[4] + f2[4] + a[4]);
        o1.y = 0.25f * (eg[5] + f1[5] + f2[5] + a[5]);
        o1.z = 0.25f * (eg[6] + f1[6] + f2[6] + a[6]);
        o1.w = 0.25f * (eg[7] + f1[7] + f2[7] + a[7]);
        float* o = out + (size_t)slot * EMB + d;
        *(float4*)o       = o0;
        *(float4*)(o + 4) = o1;
    }
}

extern "C" void kernel_launch(void* const* d_in, const int* in_sizes, int n_in,
                              void* d_out, int out_size, void* d_ws, size_t ws_size,
                              hipStream_t stream) {
    const float* user_emb = (const float*)d_in[0];
    const float* item_emb = (const float*)d_in[1];
    const int*   adj_row  = (const int*)d_in[2];
    const int*   adj_col  = (const int*)d_in[3];
    const float* adj_val  = (const float*)d_in[4];
    const int*   users    = (const int*)d_in[5];
    const int*   items    = (const int*)d_in[6];
    float*       out      = (float*)d_out;
    const int    nnz      = in_sizes[2];

    char* ws = (char*)d_ws;
    const size_t hbytes = (size_t)N_NODES * EMB; // 19.2 MB per fp8 table
    u8*  ego8 = (u8*)(ws);
    u8*  h1   = (u8*)(ws + hbytes);
    u8*  h2   = (u8*)(ws + 2 * hbytes);
    int* ptr  = (int*)(ws + 3 * hbytes);
    u32* flag = (u32*)(ws + 3 * hbytes + (size_t)(N_NODES + 64) * sizeof(int));

    // 0) clear needed-flags (ws is NOT re-poisoned between timed replays)
    (void)hipMemsetAsync(flag, 0, (size_t)N_NODES * sizeof(u32), stream);

    // 1) fused prep: row_ptr + ego->fp8
    prep_kernel<<<(nnz + 255) / 256, 256, 0, stream>>>(
        adj_row, ptr, user_emb, item_emb, (u32*)ego8, nnz);

    // 2) mark rows whose h2 is consumed
    mark_needed<<<(2 * BATCH + 3) / 4, 256, 0, stream>>>(
        users, items, adj_col, ptr, flag);

    const int spmm_blocks = (N_NODES + 3) / 4;
    const int sel_blocks  = (2 * BATCH + 3) / 4;

    // 3) h1 = A * ego8
    spmm_fp8<false><<<spmm_blocks, 256, 0, stream>>>(
        ego8, adj_col, adj_val, ptr, nullptr, h1);

    // 4) h2 = A * h1  (only rows whose output is consumed)
    spmm_fp8<true><<<spmm_blocks, 256, 0, stream>>>(
        h1, adj_col, adj_val, ptr, flag, h2);

    // 5) out = 0.25*(ego[sel] + h1[sel] + h2[sel] + (A*h2)[sel])
    finalize<<<sel_blocks, 256, 0, stream>>>(
        h1, h2, user_emb, item_emb, adj_col, adj_val, ptr, users, items, out);
}